// Round 1
// baseline (32.800 us; speedup 1.0000x reference)
//
#include <hip/hip_runtime.h>

#define B_   4
#define L_   1024
#define D_   16
#define H_   32
#define TAU_ 64
#define EMB_ 8

// ---------------------------------------------------------------------------
// Kernel 1: precompute
//   ai[b,l,h] = x[b,l,:] @ W1[0:16, h]
//   aj[b,l,h] = x[b,l,:] @ W1[16:32, h]
//   ae[t,h]   = dt_table[t,:] @ W1[32:40, h] + b1[h]   (b1 folded here)
// ---------------------------------------------------------------------------
__global__ __launch_bounds__(256) void precompute_kernel(
    const float* __restrict__ x, const float* __restrict__ dtt,
    const float* __restrict__ W1, const float* __restrict__ b1,
    float* __restrict__ ai, float* __restrict__ aj, float* __restrict__ ae)
{
    const int id = blockIdx.x * 256 + threadIdx.x;
    const int NA = B_ * L_ * H_;
    if (id < NA) {
        const int h   = id & (H_ - 1);
        const int row = id >> 5;                 // b*L + l
        const float* xr = x + row * D_;
        float s1 = 0.f, s2 = 0.f;
#pragma unroll
        for (int d = 0; d < D_; ++d) {
            const float xv = xr[d];
            s1 = fmaf(xv, W1[d * H_ + h], s1);
            s2 = fmaf(xv, W1[(D_ + d) * H_ + h], s2);
        }
        ai[id] = s1;
        aj[id] = s2;
    } else {
        const int k = id - NA;
        if (k < (TAU_ + 1) * H_) {
            const int h = k & (H_ - 1);
            const int t = k >> 5;
            float s = b1[h];
#pragma unroll
            for (int e = 0; e < EMB_; ++e)
                s = fmaf(dtt[t * EMB_ + e], W1[(2 * D_ + e) * H_ + h], s);
            ae[k] = s;
        }
    }
}

// ---------------------------------------------------------------------------
// Kernel 2: main bias kernel.
// Grid: (L/64 j-tiles, L/64 i-tiles, B). Block: 256 threads = 4 waves.
// Each thread owns one column j (lane = j offset -> coalesced stores) and
// iterates 16 rows i (wave w handles i-chunk w*16..w*16+15).
// Const-dt tiles (dt==0 or dt==64 over whole tile): fold ae row into r[].
// Band tiles: per-lane ae read from LDS, stride-33 padded (conflict-free).
// ---------------------------------------------------------------------------
__global__ __launch_bounds__(256) void bias_kernel(
    const float* __restrict__ ai, const float* __restrict__ aj,
    const float* __restrict__ ae, const float* __restrict__ W2,
    const float* __restrict__ b2p, float* __restrict__ out)
{
    __shared__ float ai_lds[64 * H_];          // 8 KB
    __shared__ float ae_lds[(TAU_ + 1) * 33];  // 8.6 KB, padded stride 33

    const int b   = blockIdx.z;
    const int i0  = blockIdx.y * 64;
    const int j0  = blockIdx.x * 64;
    const int tid = threadIdx.x;
    const int lane = tid & 63;
    const int w    = tid >> 6;
    const int j    = j0 + lane;

    // Stage ai tile (64 rows x 32 h = 2048 floats) into LDS, 2 x float4/thread.
    {
        const float4* src = (const float4*)(ai + ((size_t)(b * L_ + i0)) * H_);
        float4* dst = (float4*)ai_lds;
        dst[tid]       = src[tid];
        dst[tid + 256] = src[tid + 256];
    }

    const bool c0   = (i0 + 63 <= j0);        // dt == 0 over whole tile
    const bool c64  = (i0 >= j0 + 127);       // dt == 64 over whole tile
    const bool constpath = c0 || c64;

    float r[H_];
    const float* ajr = aj + ((size_t)(b * L_ + j)) * H_;
    if (constpath) {
        const int dtc = c0 ? 0 : TAU_;
        const float* aec = ae + dtc * H_;
#pragma unroll
        for (int h = 0; h < H_; h += 4) {
            const float4 v = *(const float4*)(ajr + h);
            const float4 e = *(const float4*)(aec + h);
            r[h + 0] = v.x + e.x; r[h + 1] = v.y + e.y;
            r[h + 2] = v.z + e.z; r[h + 3] = v.w + e.w;
        }
    } else {
#pragma unroll
        for (int h = 0; h < H_; h += 4) {
            const float4 v = *(const float4*)(ajr + h);
            r[h + 0] = v.x; r[h + 1] = v.y; r[h + 2] = v.z; r[h + 3] = v.w;
        }
        for (int k = tid; k < (TAU_ + 1) * H_; k += 256) {
            const int t = k >> 5, h = k & 31;
            ae_lds[t * 33 + h] = ae[k];
        }
    }
    __syncthreads();

    const float b2 = *b2p;
    const int  iw  = w * 16;
    float* outb = out + ((size_t)b) * L_ * L_;

    if (constpath) {
        const float pc = b2 - 0.2f * (float)(c0 ? 0 : TAU_);
        for (int ii = 0; ii < 16; ii += 4) {
            float acc0 = 0.f, acc1 = 0.f, acc2 = 0.f, acc3 = 0.f;
#pragma unroll
            for (int h = 0; h < H_; h += 4) {
                const float4 a0 = *(const float4*)&ai_lds[(iw + ii + 0) * H_ + h];
                const float4 a1 = *(const float4*)&ai_lds[(iw + ii + 1) * H_ + h];
                const float4 a2 = *(const float4*)&ai_lds[(iw + ii + 2) * H_ + h];
                const float4 a3 = *(const float4*)&ai_lds[(iw + ii + 3) * H_ + h];
                const float w0 = W2[h + 0], w1 = W2[h + 1], w2 = W2[h + 2], w3 = W2[h + 3];
                acc0 = fmaf(fmaxf(a0.x + r[h + 0], 0.f), w0, acc0);
                acc0 = fmaf(fmaxf(a0.y + r[h + 1], 0.f), w1, acc0);
                acc0 = fmaf(fmaxf(a0.z + r[h + 2], 0.f), w2, acc0);
                acc0 = fmaf(fmaxf(a0.w + r[h + 3], 0.f), w3, acc0);
                acc1 = fmaf(fmaxf(a1.x + r[h + 0], 0.f), w0, acc1);
                acc1 = fmaf(fmaxf(a1.y + r[h + 1], 0.f), w1, acc1);
                acc1 = fmaf(fmaxf(a1.z + r[h + 2], 0.f), w2, acc1);
                acc1 = fmaf(fmaxf(a1.w + r[h + 3], 0.f), w3, acc1);
                acc2 = fmaf(fmaxf(a2.x + r[h + 0], 0.f), w0, acc2);
                acc2 = fmaf(fmaxf(a2.y + r[h + 1], 0.f), w1, acc2);
                acc2 = fmaf(fmaxf(a2.z + r[h + 2], 0.f), w2, acc2);
                acc2 = fmaf(fmaxf(a2.w + r[h + 3], 0.f), w3, acc2);
                acc3 = fmaf(fmaxf(a3.x + r[h + 0], 0.f), w0, acc3);
                acc3 = fmaf(fmaxf(a3.y + r[h + 1], 0.f), w1, acc3);
                acc3 = fmaf(fmaxf(a3.z + r[h + 2], 0.f), w2, acc3);
                acc3 = fmaf(fmaxf(a3.w + r[h + 3], 0.f), w3, acc3);
            }
            const int i = i0 + iw + ii;
            outb[(size_t)(i + 0) * L_ + j] = acc0 + pc;
            outb[(size_t)(i + 1) * L_ + j] = acc1 + pc;
            outb[(size_t)(i + 2) * L_ + j] = acc2 + pc;
            outb[(size_t)(i + 3) * L_ + j] = acc3 + pc;
        }
    } else {
        for (int ii = 0; ii < 16; ++ii) {
            const int i  = i0 + iw + ii;
            const int d  = i - j;
            const int dt = d < 0 ? 0 : (d > TAU_ ? TAU_ : d);
            const float* aeL = &ae_lds[dt * 33];
            float acc = 0.f;
#pragma unroll
            for (int h = 0; h < H_; h += 4) {
                const float4 a = *(const float4*)&ai_lds[(iw + ii) * H_ + h];
                acc = fmaf(fmaxf(a.x + r[h + 0] + aeL[h + 0], 0.f), W2[h + 0], acc);
                acc = fmaf(fmaxf(a.y + r[h + 1] + aeL[h + 1], 0.f), W2[h + 1], acc);
                acc = fmaf(fmaxf(a.z + r[h + 2] + aeL[h + 2], 0.f), W2[h + 2], acc);
                acc = fmaf(fmaxf(a.w + r[h + 3] + aeL[h + 3], 0.f), W2[h + 3], acc);
            }
            outb[(size_t)i * L_ + j] = acc + b2 - 0.2f * (float)dt;
        }
    }
}

extern "C" void kernel_launch(void* const* d_in, const int* in_sizes, int n_in,
                              void* d_out, int out_size, void* d_ws, size_t ws_size,
                              hipStream_t stream) {
    const float* x   = (const float*)d_in[0];
    const float* dtt = (const float*)d_in[1];
    const float* W1  = (const float*)d_in[2];
    const float* b1  = (const float*)d_in[3];
    const float* W2  = (const float*)d_in[4];
    const float* b2  = (const float*)d_in[5];
    float* out = (float*)d_out;

    float* ws = (float*)d_ws;
    float* ai = ws;                          // B*L*H floats
    float* aj = ws + B_ * L_ * H_;           // B*L*H floats
    float* ae = ws + 2 * B_ * L_ * H_;       // 65*H floats

    const int total  = B_ * L_ * H_ + (TAU_ + 1) * H_;
    const int blocks = (total + 255) / 256;
    hipLaunchKernelGGL(precompute_kernel, dim3(blocks), dim3(256), 0, stream,
                       x, dtt, W1, b1, ai, aj, ae);

    dim3 grid(L_ / 64, L_ / 64, B_);
    hipLaunchKernelGGL(bias_kernel, grid, dim3(256), 0, stream,
                       ai, aj, ae, W2, b2, out);
}

// Round 2
// 29.485 us; speedup vs baseline: 1.1124x; 1.1124x over previous
//
#include <hip/hip_runtime.h>

#define B_   4
#define L_   1024
#define D_   16
#define H_   32
#define TAU_ 64
#define EMB_ 8

// ---------------------------------------------------------------------------
// Kernel 1: precompute
//   ai[b,l,h] = x[b,l,:] @ W1[0:16, h]
//   aj[b,l,h] = x[b,l,:] @ W1[16:32, h]
//   ae[t,h]   = dt_table[t,:] @ W1[32:40, h] + b1[h]   (b1 folded here)
// ---------------------------------------------------------------------------
__global__ __launch_bounds__(256) void precompute_kernel(
    const float* __restrict__ x, const float* __restrict__ dtt,
    const float* __restrict__ W1, const float* __restrict__ b1,
    float* __restrict__ ai, float* __restrict__ aj, float* __restrict__ ae)
{
    const int id = blockIdx.x * 256 + threadIdx.x;
    const int NA = B_ * L_ * H_;
    if (id < NA) {
        const int h   = id & (H_ - 1);
        const int row = id >> 5;                 // b*L + l
        const float* xr = x + row * D_;
        float s1 = 0.f, s2 = 0.f;
#pragma unroll
        for (int d = 0; d < D_; ++d) {
            const float xv = xr[d];
            s1 = fmaf(xv, W1[d * H_ + h], s1);
            s2 = fmaf(xv, W1[(D_ + d) * H_ + h], s2);
        }
        ai[id] = s1;
        aj[id] = s2;
    } else {
        const int k = id - NA;
        if (k < (TAU_ + 1) * H_) {
            const int h = k & (H_ - 1);
            const int t = k >> 5;
            float s = b1[h];
#pragma unroll
            for (int e = 0; e < EMB_; ++e)
                s = fmaf(dtt[t * EMB_ + e], W1[(2 * D_ + e) * H_ + h], s);
            ae[k] = s;
        }
    }
}

// ---------------------------------------------------------------------------
// Kernel 2: bias kernel, SGPR-broadcast edition.
// Grid: (L/64 j-tiles, L/64 i-tiles, B). Block: 256 = 4 waves.
// lane = j offset (coalesced stores); wave w owns rows i0+w*16 .. +15.
// The ai row is wave-uniform -> readfirstlane forces the row pointer into
// SGPRs so the compiler emits s_load (scalar path), keeping the LDS unit
// idle on const-dt tiles (225/256 of tiles). Band tiles use a stride-33
// padded LDS ae table (conflict-free b32 reads).
// ---------------------------------------------------------------------------
__global__ __launch_bounds__(256) void bias_kernel(
    const float* __restrict__ ai, const float* __restrict__ aj,
    const float* __restrict__ ae, const float* __restrict__ W2,
    const float* __restrict__ b2p, float* __restrict__ out)
{
    __shared__ float ae_lds[(TAU_ + 1) * 33];  // 8.6 KB, padded stride 33

    const int b    = blockIdx.z;
    const int i0   = blockIdx.y * 64;
    const int j0   = blockIdx.x * 64;
    const int tid  = threadIdx.x;
    const int lane = tid & 63;
    const int w    = __builtin_amdgcn_readfirstlane(tid >> 6);  // wave-uniform
    const int j    = j0 + lane;

    const bool c0   = (i0 + 63 <= j0);         // dt == 0 over whole tile
    const bool c64  = (i0 >= j0 + 128);        // dt == 64 over whole tile
    const bool constpath = c0 || c64;

    // Hoist W2 (uniform -> scalar regs) and b2.
    float w2[H_];
#pragma unroll
    for (int h = 0; h < H_; h += 4) {
        const float4 t = *(const float4*)(W2 + h);
        w2[h] = t.x; w2[h + 1] = t.y; w2[h + 2] = t.z; w2[h + 3] = t.w;
    }
    const float b2 = *b2p;

    // Per-lane column vector r[h] = aj[j,h] (+ ae[dtc,h] on const path).
    float r[H_];
    const float* ajr = aj + ((size_t)(b * L_ + j)) * H_;
    if (constpath) {
        const float* aec = ae + (c0 ? 0 : TAU_) * H_;   // uniform -> sgpr
#pragma unroll
        for (int h = 0; h < H_; h += 4) {
            const float4 v = *(const float4*)(ajr + h);
            r[h + 0] = v.x + aec[h + 0];
            r[h + 1] = v.y + aec[h + 1];
            r[h + 2] = v.z + aec[h + 2];
            r[h + 3] = v.w + aec[h + 3];
        }
    } else {
#pragma unroll
        for (int h = 0; h < H_; h += 4) {
            const float4 v = *(const float4*)(ajr + h);
            r[h + 0] = v.x; r[h + 1] = v.y; r[h + 2] = v.z; r[h + 3] = v.w;
        }
        for (int k = tid; k < (TAU_ + 1) * H_; k += 256) {
            const int t = k >> 5, h = k & 31;
            ae_lds[t * 33 + h] = ae[k];
        }
        __syncthreads();   // block-uniform branch: all threads take this path
    }

    // Wave-uniform base pointer for this wave's 16 ai rows -> scalar loads.
    const float* aiBase = ai + ((size_t)(b * L_ + i0 + w * 16)) * H_;
    float* outb = out + ((size_t)b) * L_ * L_ + ((size_t)(i0 + w * 16)) * L_ + j;

    if (constpath) {
        const float pc = b2 - 0.2f * (c0 ? 0.f : (float)TAU_);
        for (int ii = 0; ii < 16; ii += 2) {       // 2 rows/iter for ILP
            const float* ar0 = aiBase + (ii + 0) * H_;
            const float* ar1 = aiBase + (ii + 1) * H_;
            float a0 = 0.f, a0b = 0.f, a1 = 0.f, a1b = 0.f;
#pragma unroll
            for (int h = 0; h < H_; h += 2) {
                a0  = fmaf(fmaxf(ar0[h + 0] + r[h + 0], 0.f), w2[h + 0], a0);
                a0b = fmaf(fmaxf(ar0[h + 1] + r[h + 1], 0.f), w2[h + 1], a0b);
                a1  = fmaf(fmaxf(ar1[h + 0] + r[h + 0], 0.f), w2[h + 0], a1);
                a1b = fmaf(fmaxf(ar1[h + 1] + r[h + 1], 0.f), w2[h + 1], a1b);
            }
            __builtin_nontemporal_store(a0 + a0b + pc, outb + (size_t)(ii + 0) * L_);
            __builtin_nontemporal_store(a1 + a1b + pc, outb + (size_t)(ii + 1) * L_);
        }
    } else {
        for (int ii = 0; ii < 16; ++ii) {
            const int i  = i0 + w * 16 + ii;
            const int d  = i - j;
            const int dt = d < 0 ? 0 : (d > TAU_ ? TAU_ : d);
            const float* aeL = &ae_lds[dt * 33];
            const float* ar  = aiBase + ii * H_;
            float acc0 = 0.f, acc1 = 0.f;
#pragma unroll
            for (int h = 0; h < H_; h += 2) {
                acc0 = fmaf(fmaxf(ar[h + 0] + r[h + 0] + aeL[h + 0], 0.f), w2[h + 0], acc0);
                acc1 = fmaf(fmaxf(ar[h + 1] + r[h + 1] + aeL[h + 1], 0.f), w2[h + 1], acc1);
            }
            __builtin_nontemporal_store(acc0 + acc1 + b2 - 0.2f * (float)dt,
                                        outb + (size_t)ii * L_);
        }
    }
}

extern "C" void kernel_launch(void* const* d_in, const int* in_sizes, int n_in,
                              void* d_out, int out_size, void* d_ws, size_t ws_size,
                              hipStream_t stream) {
    const float* x   = (const float*)d_in[0];
    const float* dtt = (const float*)d_in[1];
    const float* W1  = (const float*)d_in[2];
    const float* b1  = (const float*)d_in[3];
    const float* W2  = (const float*)d_in[4];
    const float* b2  = (const float*)d_in[5];
    float* out = (float*)d_out;

    float* ws = (float*)d_ws;
    float* ai = ws;                          // B*L*H floats
    float* aj = ws + B_ * L_ * H_;           // B*L*H floats
    float* ae = ws + 2 * B_ * L_ * H_;       // 65*H floats

    const int total  = B_ * L_ * H_ + (TAU_ + 1) * H_;
    const int blocks = (total + 255) / 256;
    hipLaunchKernelGGL(precompute_kernel, dim3(blocks), dim3(256), 0, stream,
                       x, dtt, W1, b1, ai, aj, ae);

    dim3 grid(L_ / 64, L_ / 64, B_);
    hipLaunchKernelGGL(bias_kernel, grid, dim3(256), 0, stream,
                       ai, aj, ae, W2, b2, out);
}

// Round 3
// 29.464 us; speedup vs baseline: 1.1132x; 1.0007x over previous
//
#include <hip/hip_runtime.h>

#define B_   4
#define L_   1024
#define D_   16
#define H_   32
#define TAU_ 64
#define EMB_ 8
#define AEP_ 34   // ae_lds padded stride: even -> 8B-aligned b64 reads, 2-way banks (free)

// ---------------------------------------------------------------------------
// Kernel 1: precompute
//   ai[b,l,h] = x[b,l,:] @ W1[0:16, h]
//   aj[b,l,h] = x[b,l,:] @ W1[16:32, h]
//   ae[t,h]   = dt_table[t,:] @ W1[32:40, h] + b1[h]   (b1 folded here)
// ---------------------------------------------------------------------------
__global__ __launch_bounds__(256) void precompute_kernel(
    const float* __restrict__ x, const float* __restrict__ dtt,
    const float* __restrict__ W1, const float* __restrict__ b1,
    float* __restrict__ ai, float* __restrict__ aj, float* __restrict__ ae)
{
    const int id = blockIdx.x * 256 + threadIdx.x;
    const int NA = B_ * L_ * H_;
    if (id < NA) {
        const int h   = id & (H_ - 1);
        const int row = id >> 5;                 // b*L + l
        const float4* xr4 = (const float4*)(x + row * D_);
        const float4 v0 = xr4[0], v1 = xr4[1], v2 = xr4[2], v3 = xr4[3];
        float xv[D_];
        xv[0]=v0.x; xv[1]=v0.y; xv[2]=v0.z; xv[3]=v0.w;
        xv[4]=v1.x; xv[5]=v1.y; xv[6]=v1.z; xv[7]=v1.w;
        xv[8]=v2.x; xv[9]=v2.y; xv[10]=v2.z; xv[11]=v2.w;
        xv[12]=v3.x; xv[13]=v3.y; xv[14]=v3.z; xv[15]=v3.w;
        float s1 = 0.f, s2 = 0.f;
#pragma unroll
        for (int d = 0; d < D_; ++d) {
            s1 = fmaf(xv[d], W1[d * H_ + h], s1);
            s2 = fmaf(xv[d], W1[(D_ + d) * H_ + h], s2);
        }
        ai[id] = s1;
        aj[id] = s2;
    } else {
        const int k = id - NA;
        if (k < (TAU_ + 1) * H_) {
            const int h = k & (H_ - 1);
            const int t = k >> 5;
            float s = b1[h];
#pragma unroll
            for (int e = 0; e < EMB_; ++e)
                s = fmaf(dtt[t * EMB_ + e], W1[(2 * D_ + e) * H_ + h], s);
            ae[k] = s;
        }
    }
}

// ---------------------------------------------------------------------------
// Kernel 2: bias kernel, register-lean edition.
// __launch_bounds__(256,4): cap VGPR at 128 -> guaranteed 4 waves/SIMD
// (16 waves/CU) so L2/scalar-load latency is hidden by TLP.
// W2/b2/ai-rows are wave-uniform -> read in-loop from uniform pointers so
// they live in SGPRs (s_load), not VGPRs. Only r[32] + 4 accs are VGPRs.
// ---------------------------------------------------------------------------
__global__ __launch_bounds__(256, 4) void bias_kernel(
    const float* __restrict__ ai, const float* __restrict__ aj,
    const float* __restrict__ ae, const float* __restrict__ W2,
    const float* __restrict__ b2p, float* __restrict__ out)
{
    __shared__ float ae_lds[(TAU_ + 1) * AEP_];   // ~8.8 KB

    const int b    = blockIdx.z;
    const int i0   = blockIdx.y * 64;
    const int j0   = blockIdx.x * 64;
    const int tid  = threadIdx.x;
    const int lane = tid & 63;
    const int w    = __builtin_amdgcn_readfirstlane(tid >> 6);  // wave-uniform
    const int j    = j0 + lane;

    const bool c0   = (j0 >= i0 + 64);         // dt == 0 over whole tile
    const bool c64  = (i0 >= j0 + 128);        // dt == 64 over whole tile
    const bool constpath = c0 || c64;

    const float b2 = *b2p;                     // uniform -> sgpr

    // Per-lane column vector r[h] = aj[j,h] (+ ae[dtc,h] on const path).
    float r[H_];
    {
        const float* ajr = aj + ((size_t)(b * L_ + j)) * H_;
#pragma unroll
        for (int h = 0; h < H_; h += 4) {
            const float4 v = *(const float4*)(ajr + h);
            r[h + 0] = v.x; r[h + 1] = v.y; r[h + 2] = v.z; r[h + 3] = v.w;
        }
    }

    if (constpath) {
        const float* aec = ae + (c0 ? 0 : TAU_) * H_;   // uniform -> s_load
#pragma unroll
        for (int h = 0; h < H_; ++h) r[h] += aec[h];
    } else {
        for (int k = tid; k < (TAU_ + 1) * H_; k += 256)
            ae_lds[(k >> 5) * AEP_ + (k & 31)] = ae[k];
        __syncthreads();   // block-uniform branch: all threads take this path
    }

    // Wave-uniform base pointer for this wave's 16 ai rows -> scalar loads.
    const float* aiBase = ai + ((size_t)(b * L_ + i0 + w * 16)) * H_;
    float* outb = out + ((size_t)b) * L_ * L_ + ((size_t)(i0 + w * 16)) * L_ + j;

    if (constpath) {
        const float pc = b2 - 0.2f * (c0 ? 0.f : (float)TAU_);
        for (int ii = 0; ii < 16; ii += 2) {       // 2 rows/iter, 4 accs for ILP
            const float* ar0 = aiBase + (ii + 0) * H_;   // uniform -> s_load
            const float* ar1 = aiBase + (ii + 1) * H_;
            float a0x = 0.f, a0y = 0.f, a1x = 0.f, a1y = 0.f;
#pragma unroll
            for (int h = 0; h < H_; h += 2) {
                const float w0 = W2[h], w1 = W2[h + 1];  // uniform -> sgpr
                a0x = fmaf(fmaxf(ar0[h + 0] + r[h + 0], 0.f), w0, a0x);
                a0y = fmaf(fmaxf(ar0[h + 1] + r[h + 1], 0.f), w1, a0y);
                a1x = fmaf(fmaxf(ar1[h + 0] + r[h + 0], 0.f), w0, a1x);
                a1y = fmaf(fmaxf(ar1[h + 1] + r[h + 1], 0.f), w1, a1y);
            }
            __builtin_nontemporal_store(a0x + a0y + pc, outb + (size_t)(ii + 0) * L_);
            __builtin_nontemporal_store(a1x + a1y + pc, outb + (size_t)(ii + 1) * L_);
        }
    } else {
        for (int ii = 0; ii < 16; ++ii) {
            const int i  = i0 + w * 16 + ii;
            const int d  = i - j;
            const int dt = d < 0 ? 0 : (d > TAU_ ? TAU_ : d);
            const float2* aeL = (const float2*)&ae_lds[dt * AEP_];  // 8B aligned
            const float* ar  = aiBase + ii * H_;
            float accx = 0.f, accy = 0.f;
#pragma unroll
            for (int h = 0; h < H_; h += 2) {
                const float2 e = aeL[h >> 1];
                accx = fmaf(fmaxf(ar[h + 0] + r[h + 0] + e.x, 0.f), W2[h + 0], accx);
                accy = fmaf(fmaxf(ar[h + 1] + r[h + 1] + e.y, 0.f), W2[h + 1], accy);
            }
            __builtin_nontemporal_store(accx + accy + b2 - 0.2f * (float)dt,
                                        outb + (size_t)ii * L_);
        }
    }
}

extern "C" void kernel_launch(void* const* d_in, const int* in_sizes, int n_in,
                              void* d_out, int out_size, void* d_ws, size_t ws_size,
                              hipStream_t stream) {
    const float* x   = (const float*)d_in[0];
    const float* dtt = (const float*)d_in[1];
    const float* W1  = (const float*)d_in[2];
    const float* b1  = (const float*)d_in[3];
    const float* W2  = (const float*)d_in[4];
    const float* b2  = (const float*)d_in[5];
    float* out = (float*)d_out;

    float* ws = (float*)d_ws;
    float* ai = ws;                          // B*L*H floats
    float* aj = ws + B_ * L_ * H_;           // B*L*H floats
    float* ae = ws + 2 * B_ * L_ * H_;       // 65*H floats

    const int total  = B_ * L_ * H_ + (TAU_ + 1) * H_;
    const int blocks = (total + 255) / 256;
    hipLaunchKernelGGL(precompute_kernel, dim3(blocks), dim3(256), 0, stream,
                       x, dtt, W1, b1, ai, aj, ae);

    dim3 grid(L_ / 64, L_ / 64, B_);
    hipLaunchKernelGGL(bias_kernel, grid, dim3(256), 0, stream,
                       ai, aj, ae, W2, b2, out);
}